// Round 5
// baseline (969.781 us; speedup 1.0000x reference)
//
#include <hip/hip_runtime.h>
#include <hip/hip_bf16.h>

#define L_SEQ 2048
#define HIDN  2048
#define NH    32
#define BATCHN 4

using bf16x8 = __attribute__((ext_vector_type(8))) short;
using f32x4  = __attribute__((ext_vector_type(4))) float;

__device__ __forceinline__ unsigned short f2bf(float f) {
  union { float f; unsigned u; } v; v.f = f;
  unsigned r = v.u + 0x7fffu + ((v.u >> 16) & 1u);
  return (unsigned short)(r >> 16);
}

__device__ __forceinline__ void gl_lds16(const void* g, void* l) {
  __builtin_amdgcn_global_load_lds(
      (const __attribute__((address_space(1))) unsigned int*)g,
      (__attribute__((address_space(3))) unsigned int*)l, 16, 0, 0);
}

__device__ __forceinline__ float bperm_f(int byte_addr, float v) {
  int r = __builtin_amdgcn_ds_bpermute(byte_addr, __builtin_bit_cast(int, v));
  return __builtin_bit_cast(float, r);
}

// ---------------- f32 -> bf16 convert (grid-stride over n/4 float4s) ----------
__global__ __launch_bounds__(256) void cvt_bf16_k(const float* __restrict__ in,
                                                  unsigned short* __restrict__ out, int n4) {
  for (int i = blockIdx.x * 256 + threadIdx.x; i < n4; i += gridDim.x * 256) {
    float4 v = *(const float4*)&in[(size_t)i * 4];
    ushort4 o;
    o.x = f2bf(v.x); o.y = f2bf(v.y); o.z = f2bf(v.z); o.w = f2bf(v.w);
    *(ushort4*)&out[(size_t)i * 4] = o;
  }
}

// -------- conv weight transform: wreT[o][k*64+i] = conv_w[o][i][k] (bf16) -----
__global__ __launch_bounds__(256) void wret_k(const float* __restrict__ cw,
                                              unsigned short* __restrict__ out) {
  int idx = blockIdx.x * 256 + threadIdx.x;   // 2048*256 total
  int o = idx >> 8, q = idx & 255;
  int k = q >> 6, i = q & 63;
  out[idx] = f2bf(cw[o * 256 + i * 4 + k]);
}

// ---------------- GEMM: OUT[m][n] = sum_k X[m][k]*W[n][k], bf16 MFMA ----------
template <int SILU>
__global__ __launch_bounds__(256) void gemm_xwt_k(const unsigned short* __restrict__ X,
                                                  const unsigned short* __restrict__ W,
                                                  float* __restrict__ OUT,
                                                  int M, int N, int K) {
  __shared__ __align__(16) unsigned short As[128 * 32];
  __shared__ __align__(16) unsigned short Bs[128 * 32];
  const int tid = threadIdx.x, lane = tid & 63, wid = tid >> 6;
  const int wm = wid >> 1, wn = wid & 1;
  const int m0 = blockIdx.x * 128, n0 = blockIdx.y * 128;
  const int fr = lane & 15, kg = lane >> 4;
  const int sr = lane >> 2, sc = (lane & 3) * 8;   // staging: 4 lanes per row
  f32x4 acc[4][4] = {};
  for (int k0 = 0; k0 < K; k0 += 32) {
    const int cA0 = wid * 16, cA1 = (wid + 4) * 16;   // 16-row chunks per wave-call
    gl_lds16(&X[(size_t)(m0 + cA0 + sr) * K + k0 + sc], &As[cA0 * 32]);
    gl_lds16(&X[(size_t)(m0 + cA1 + sr) * K + k0 + sc], &As[cA1 * 32]);
    gl_lds16(&W[(size_t)(n0 + cA0 + sr) * K + k0 + sc], &Bs[cA0 * 32]);
    gl_lds16(&W[(size_t)(n0 + cA1 + sr) * K + k0 + sc], &Bs[cA1 * 32]);
    __syncthreads();
    bf16x8 af[4], bfr[4];
#pragma unroll
    for (int t = 0; t < 4; ++t) {
      af[t]  = *(const bf16x8*)&As[(wm * 64 + t * 16 + fr) * 32 + kg * 8];
      bfr[t] = *(const bf16x8*)&Bs[(wn * 64 + t * 16 + fr) * 32 + kg * 8];
    }
#pragma unroll
    for (int mt = 0; mt < 4; ++mt)
#pragma unroll
      for (int nt = 0; nt < 4; ++nt)
        acc[mt][nt] = __builtin_amdgcn_mfma_f32_16x16x32_bf16(af[mt], bfr[nt], acc[mt][nt], 0, 0, 0);
    __syncthreads();
  }
#pragma unroll
  for (int mt = 0; mt < 4; ++mt)
#pragma unroll
    for (int nt = 0; nt < 4; ++nt) {
      const int col = n0 + wn * 64 + nt * 16 + fr;
#pragma unroll
      for (int r = 0; r < 4; ++r) {
        const int row = m0 + wm * 64 + mt * 16 + kg * 4 + r;
        float v = acc[mt][nt][r];
        if (SILU) v = v / (1.f + __expf(-v));
        OUT[(size_t)row * N + col] = v;
      }
    }
}

// ------- grouped causal conv as MFMA GEMM; epilogue: (Bc+bias)*dt -> dB -------
__global__ __launch_bounds__(256) void conv_k(const unsigned short* __restrict__ xb,
                                              const unsigned short* __restrict__ wreT,
                                              const float* __restrict__ conv_b,
                                              const float* __restrict__ dt,
                                              float* __restrict__ dB) {
  __shared__ __align__(16) unsigned short x_lds[67 * 64];
  const int l0 = blockIdx.x * 64, g = blockIdx.y, b = blockIdx.z;
  const int tid = threadIdx.x, lane = tid & 63, wid = tid >> 6;
  {
    const int r = tid >> 3, ch = (tid & 7) * 8;
#pragma unroll
    for (int pass = 0; pass < 3; ++pass) {
      int rr = r + pass * 32;
      if (rr < 67) {
        int lg = l0 - 3 + rr;
        bf16x8 v = {};
        if (lg >= 0) v = *(const bf16x8*)&xb[(size_t)(b * L_SEQ + lg) * HIDN + g * 64 + ch];
        *(bf16x8*)&x_lds[rr * 64 + ch] = v;
      }
    }
  }
  __syncthreads();
  const int fr = lane & 15, kg = lane >> 4, wm = wid;
  f32x4 acc[4] = {};
#pragma unroll
  for (int ks = 0; ks < 8; ++ks) {
    bf16x8 a = *(const bf16x8*)&x_lds[(wm * 16 + fr + (ks >> 1)) * 64 + (ks & 1) * 32 + kg * 8];
#pragma unroll
    for (int nt = 0; nt < 4; ++nt) {
      bf16x8 bq = *(const bf16x8*)&wreT[(size_t)(g * 64 + nt * 16 + fr) * 256 + ks * 32 + kg * 8];
      acc[nt] = __builtin_amdgcn_mfma_f32_16x16x32_bf16(a, bq, acc[nt], 0, 0, 0);
    }
  }
#pragma unroll
  for (int nt = 0; nt < 4; ++nt) {
    const int o = nt * 16 + fr;
    const float bias = conv_b[g * 64 + o];
#pragma unroll
    for (int r = 0; r < 4; ++r) {
      const int lg = l0 + wm * 16 + kg * 4 + r;
      const float dtv = dt[b * L_SEQ + lg];
      dB[((size_t)(b * NH + g) * L_SEQ + lg) * 64 + o] = (acc[nt][r] + bias) * dtv;
    }
  }
}

// ------- selective scan v4: ONE wave per (b,h), MFMA matvec, no LDS/barriers --
// Lane S holds master state s[mS] (f32), mS = 16*((S&15)>>2) + 4*(S>>4) + (S&3).
// This layout makes lane S's own new dot extractable from its MFMA acc regs via
// a 15-cndmask compile-time tree: export(S) = acc[(S&15)>>2][S&3] = dot[mS].
// B-fragment (s replicated across cols) built by 16 in-wave ds_bpermute +
// 8 v_cvt_pk_bf16_f32. dB/dt prefetched 2 groups (8 steps) ahead in registers.
__global__ __launch_bounds__(64) void scan_k(const float* __restrict__ dB,
                                             const float* __restrict__ Aw,
                                             const float* __restrict__ dt,
                                             unsigned short* __restrict__ states) {
  const int bid = blockIdx.x;          // b*32 + h
  const int h = bid & 31, b = bid >> 5;
  const int lane = threadIdx.x;        // 0..63
  const int fr = lane & 15, kg = lane >> 4;
  const int mS = (((lane & 15) >> 2) << 4) + ((lane >> 4) << 2) + (lane & 3);

  // ---- preload A fragments: afr[mt][kt] holds A[h][mt*16+fr][kt*32+kg*8+j] ---
  bf16x8 afr[4][2];
  const float* Ah = Aw + (size_t)h * 64 * 64;
#pragma unroll
  for (int mt = 0; mt < 4; ++mt)
#pragma unroll
    for (int kt = 0; kt < 2; ++kt) {
      const float* p = &Ah[(size_t)(mt * 16 + fr) * 64 + kt * 32 + kg * 8];
      float4 v0 = *(const float4*)p;
      float4 v1 = *(const float4*)(p + 4);
      bf16x8 f;
      f[0] = (short)f2bf(v0.x); f[1] = (short)f2bf(v0.y);
      f[2] = (short)f2bf(v0.z); f[3] = (short)f2bf(v0.w);
      f[4] = (short)f2bf(v1.x); f[5] = (short)f2bf(v1.y);
      f[6] = (short)f2bf(v1.z); f[7] = (short)f2bf(v1.w);
      afr[mt][kt] = f;
    }

  // ---- bpermute byte-addresses for B-frag build: lane needs s[kg*8+j] (kt0)
  // and s[32+kg*8+j] (kt1); s[k] lives at lane 16*((k>>2)&3)+4*(k>>4)+(k&3).
  int bpa[16];
#pragma unroll
  for (int j = 0; j < 8; ++j) {
    int k0 = kg * 8 + j;
    int k1 = k0 + 32;
    bpa[j]     = ((((k0 & 15) >> 2) << 4) + ((k0 >> 4) << 2) + (k0 & 3)) << 2;
    bpa[8 + j] = ((((k1 & 15) >> 2) << 4) + ((k1 >> 4) << 2) + (k1 & 3)) << 2;
  }

  const float* dBp = dB + (size_t)bid * L_SEQ * 64 + mS;
  unsigned short* stp = states + (size_t)bid * L_SEQ * 64 + mS;
  const float* dtp = dt + b * L_SEQ;

  // prefetch rings (2 groups = 8 steps ahead)
  float r0[4], r1[4];
#pragma unroll
  for (int u = 0; u < 4; ++u) r0[u] = dBp[(size_t)u * 64];
#pragma unroll
  for (int u = 0; u < 4; ++u) r1[u] = dBp[(size_t)(4 + u) * 64];
  float4 dtc = *(const float4*)&dtp[0];
  float4 dtn = *(const float4*)&dtp[4];

  float s = 0.f;
  for (int g = 0; g < L_SEQ / 4; ++g) {
    const int l0 = g * 4;
    const int lp = (l0 + 8 <= L_SEQ - 4) ? (l0 + 8) : (L_SEQ - 4);
    float rn[4];
#pragma unroll
    for (int u = 0; u < 4; ++u) rn[u] = dBp[(size_t)(lp + u) * 64];
    float4 dtn2 = *(const float4*)&dtp[lp];
    float dtv[4] = { dtc.x * 1.44269504f, dtc.y * 1.44269504f,
                     dtc.z * 1.44269504f, dtc.w * 1.44269504f };
#pragma unroll
    for (int u = 0; u < 4; ++u) {
      // ---- build B fragments from current s (in-wave, no barrier) ----
      float sv0 = bperm_f(bpa[0], s), sv1 = bperm_f(bpa[1], s);
      float sv2 = bperm_f(bpa[2], s), sv3 = bperm_f(bpa[3], s);
      float sv4 = bperm_f(bpa[4], s), sv5 = bperm_f(bpa[5], s);
      float sv6 = bperm_f(bpa[6], s), sv7 = bperm_f(bpa[7], s);
      float sw0 = bperm_f(bpa[8], s), sw1 = bperm_f(bpa[9], s);
      float sw2 = bperm_f(bpa[10], s), sw3 = bperm_f(bpa[11], s);
      float sw4 = bperm_f(bpa[12], s), sw5 = bperm_f(bpa[13], s);
      float sw6 = bperm_f(bpa[14], s), sw7 = bperm_f(bpa[15], s);
      union { bf16x8 v; unsigned u32[4]; } b0, b1;
      asm("v_cvt_pk_bf16_f32 %0, %1, %2" : "=v"(b0.u32[0]) : "v"(sv0), "v"(sv1));
      asm("v_cvt_pk_bf16_f32 %0, %1, %2" : "=v"(b0.u32[1]) : "v"(sv2), "v"(sv3));
      asm("v_cvt_pk_bf16_f32 %0, %1, %2" : "=v"(b0.u32[2]) : "v"(sv4), "v"(sv5));
      asm("v_cvt_pk_bf16_f32 %0, %1, %2" : "=v"(b0.u32[3]) : "v"(sv6), "v"(sv7));
      asm("v_cvt_pk_bf16_f32 %0, %1, %2" : "=v"(b1.u32[0]) : "v"(sw0), "v"(sw1));
      asm("v_cvt_pk_bf16_f32 %0, %1, %2" : "=v"(b1.u32[1]) : "v"(sw2), "v"(sw3));
      asm("v_cvt_pk_bf16_f32 %0, %1, %2" : "=v"(b1.u32[2]) : "v"(sw4), "v"(sw5));
      asm("v_cvt_pk_bf16_f32 %0, %1, %2" : "=v"(b1.u32[3]) : "v"(sw6), "v"(sw7));
      // ---- matvec: dot[m] = A·s via 8 MFMAs ----
      f32x4 z = {0.f, 0.f, 0.f, 0.f};
      f32x4 a0 = __builtin_amdgcn_mfma_f32_16x16x32_bf16(afr[0][0], b0.v, z, 0, 0, 0);
      f32x4 a1 = __builtin_amdgcn_mfma_f32_16x16x32_bf16(afr[1][0], b0.v, z, 0, 0, 0);
      f32x4 a2 = __builtin_amdgcn_mfma_f32_16x16x32_bf16(afr[2][0], b0.v, z, 0, 0, 0);
      f32x4 a3 = __builtin_amdgcn_mfma_f32_16x16x32_bf16(afr[3][0], b0.v, z, 0, 0, 0);
      a0 = __builtin_amdgcn_mfma_f32_16x16x32_bf16(afr[0][1], b1.v, a0, 0, 0, 0);
      a1 = __builtin_amdgcn_mfma_f32_16x16x32_bf16(afr[1][1], b1.v, a1, 0, 0, 0);
      a2 = __builtin_amdgcn_mfma_f32_16x16x32_bf16(afr[2][1], b1.v, a2, 0, 0, 0);
      a3 = __builtin_amdgcn_mfma_f32_16x16x32_bf16(afr[3][1], b1.v, a3, 0, 0, 0);
      // ---- export tree: this lane's dot[mS] = acc[(S&15)>>2][S&3] ----
      float x00 = (lane & 1) ? a0[1] : a0[0];
      float x01 = (lane & 1) ? a0[3] : a0[2];
      float x10 = (lane & 1) ? a1[1] : a1[0];
      float x11 = (lane & 1) ? a1[3] : a1[2];
      float x20 = (lane & 1) ? a2[1] : a2[0];
      float x21 = (lane & 1) ? a2[3] : a2[2];
      float x30 = (lane & 1) ? a3[1] : a3[0];
      float x31 = (lane & 1) ? a3[3] : a3[2];
      float y0 = (lane & 2) ? x01 : x00;
      float y1 = (lane & 2) ? x11 : x10;
      float y2 = (lane & 2) ? x21 : x20;
      float y3 = (lane & 2) ? x31 : x30;
      float z0 = (lane & 4) ? y1 : y0;
      float z1 = (lane & 4) ? y3 : y2;
      float dot = (lane & 8) ? z1 : z0;
      // ---- state update ----
      const float e = __builtin_amdgcn_exp2f(dot * dtv[u]);
      s = e * s + r0[u];
      unsigned sb;
      asm("v_cvt_pk_bf16_f32 %0, %1, %2" : "=v"(sb) : "v"(s), "v"(s));
      stp[(size_t)(l0 + u) * 64] = (unsigned short)sb;
    }
#pragma unroll
    for (int u = 0; u < 4; ++u) { r0[u] = r1[u]; r1[u] = rn[u]; }
    dtc = dtn; dtn = dtn2;
  }
}

// ----- C projection + x*D + silu(gate) multiply; writes hs1 (b,l,hid) f32 -----
__global__ __launch_bounds__(256) void proj_k(const unsigned short* __restrict__ st,
                                              const unsigned short* __restrict__ cwb,
                                              const float* __restrict__ xin,
                                              const float* __restrict__ Dp,
                                              const float* __restrict__ gs,
                                              float* __restrict__ hs1) {
  const int l0 = blockIdx.x * 64, h = blockIdx.y, b = blockIdx.z;
  const int tid = threadIdx.x, lane = tid & 63, wid = tid >> 6;
  const int fr = lane & 15, kg = lane >> 4, wm = wid;
  f32x4 acc[4] = {};
#pragma unroll
  for (int ks = 0; ks < 2; ++ks) {
    bf16x8 a = *(const bf16x8*)&st[((size_t)(b * NH + h) * L_SEQ + l0 + wm * 16 + fr) * 64 + ks * 32 + kg * 8];
#pragma unroll
    for (int nt = 0; nt < 4; ++nt) {
      bf16x8 bq = *(const bf16x8*)&cwb[(size_t)(h * 64 + nt * 16 + fr) * 64 + ks * 32 + kg * 8];
      acc[nt] = __builtin_amdgcn_mfma_f32_16x16x32_bf16(a, bq, acc[nt], 0, 0, 0);
    }
  }
  const float Dh = Dp[h];
#pragma unroll
  for (int nt = 0; nt < 4; ++nt) {
    const int ccol = h * 64 + nt * 16 + fr;
#pragma unroll
    for (int r = 0; r < 4; ++r) {
      const int lg = l0 + wm * 16 + kg * 4 + r;
      const size_t idx = (size_t)(b * L_SEQ + lg) * HIDN + ccol;
      float v = acc[nt][r] + xin[idx] * Dh;
      hs1[idx] = v * gs[idx];
    }
  }
}

// --------------------- gated RMSNorm -> bf16 rows -----------------------------
__global__ __launch_bounds__(256) void norm_k(const float* __restrict__ hs1,
                                              const float* __restrict__ nw,
                                              unsigned short* __restrict__ out) {
  const int row = blockIdx.x;
  const float* p = hs1 + (size_t)row * HIDN;
  const int c0 = threadIdx.x * 8;
  float4 u0 = *(const float4*)&p[c0];
  float4 u1 = *(const float4*)&p[c0 + 4];
  float ss = u0.x * u0.x + u0.y * u0.y + u0.z * u0.z + u0.w * u0.w +
             u1.x * u1.x + u1.y * u1.y + u1.z * u1.z + u1.w * u1.w;
#pragma unroll
  for (int off = 32; off; off >>= 1) ss += __shfl_xor(ss, off);
  __shared__ float pr[4];
  if ((threadIdx.x & 63) == 0) pr[threadIdx.x >> 6] = ss;
  __syncthreads();
  float tot = pr[0] + pr[1] + pr[2] + pr[3];
  float rs = rsqrtf(tot * (1.f / HIDN) + 1e-6f);
  bf16x8 res;
  res[0] = (short)f2bf(nw[c0 + 0] * u0.x * rs);
  res[1] = (short)f2bf(nw[c0 + 1] * u0.y * rs);
  res[2] = (short)f2bf(nw[c0 + 2] * u0.z * rs);
  res[3] = (short)f2bf(nw[c0 + 3] * u0.w * rs);
  res[4] = (short)f2bf(nw[c0 + 4] * u1.x * rs);
  res[5] = (short)f2bf(nw[c0 + 5] * u1.y * rs);
  res[6] = (short)f2bf(nw[c0 + 6] * u1.z * rs);
  res[7] = (short)f2bf(nw[c0 + 7] * u1.w * rs);
  *(bf16x8*)&out[(size_t)row * HIDN + c0] = res;
}

extern "C" void kernel_launch(void* const* d_in, const int* in_sizes, int n_in,
                              void* d_out, int out_size, void* d_ws, size_t ws_size,
                              hipStream_t stream) {
  const float* x  = (const float*)d_in[0];
  const float* dt = (const float*)d_in[1];
  const float* gw = (const float*)d_in[2];
  const float* Aw = (const float*)d_in[3];
  const float* cw = (const float*)d_in[4];
  const float* cb = (const float*)d_in[5];
  const float* Cw = (const float*)d_in[6];
  const float* Dp = (const float*)d_in[7];
  const float* nw = (const float*)d_in[8];
  const float* ow = (const float*)d_in[9];
  float* out = (float*)d_out;

  // workspace layout (bytes); x_bf16 region is reused for states after conv.
  char* w = (char*)d_ws;
  unsigned short* xb   = (unsigned short*)(w);                // 32MB
  unsigned short* stb  = (unsigned short*)(w);                // overlay (after conv)
  unsigned short* gwb  = (unsigned short*)(w + 33554432);     // 8MB
  unsigned short* owb  = (unsigned short*)(w + 41943040);     // 8MB
  unsigned short* wret = (unsigned short*)(w + 50331648);     // 1MB
  unsigned short* cwb  = (unsigned short*)(w + 51380224);     // 256KB
  float*          dBf  = (float*)(w + 52428800);              // 64MB
  float*          hs1  = dBf;                                 // overlay (after scan)
  unsigned short* hsb  = (unsigned short*)(w + 119537664);    // 32MB
  if (ws_size < 153092096) return;

  cvt_bf16_k<<<2048, 256, 0, stream>>>(x, xb, 16777216 / 4);
  cvt_bf16_k<<<1024, 256, 0, stream>>>(gw, gwb, 4194304 / 4);
  cvt_bf16_k<<<1024, 256, 0, stream>>>(ow, owb, 4194304 / 4);
  cvt_bf16_k<<<128, 256, 0, stream>>>(Cw, cwb, 131072 / 4);
  wret_k<<<2048, 256, 0, stream>>>(cw, wret);

  dim3 gg(8192 / 128, 2048 / 128);
  gemm_xwt_k<1><<<gg, 256, 0, stream>>>(xb, gwb, out, 8192, 2048, 2048);  // silu(gate) -> d_out
  conv_k<<<dim3(32, 32, 4), 256, 0, stream>>>(xb, wret, cb, dt, dBf);
  scan_k<<<128, 64, 0, stream>>>(dBf, Aw, dt, stb);
  proj_k<<<dim3(32, 32, 4), 256, 0, stream>>>(stb, cwb, x, Dp, out, hs1);
  norm_k<<<8192, 256, 0, stream>>>(hs1, nw, hsb);
  gemm_xwt_k<0><<<gg, 256, 0, stream>>>(hsb, owb, out, 8192, 2048, 2048);
}

// Round 6
// 882.919 us; speedup vs baseline: 1.0984x; 1.0984x over previous
//
#include <hip/hip_runtime.h>
#include <hip/hip_bf16.h>

#define L_SEQ 2048
#define HIDN  2048
#define NH    32
#define BATCHN 4

using bf16x8 = __attribute__((ext_vector_type(8))) short;
using f32x4  = __attribute__((ext_vector_type(4))) float;

__device__ __forceinline__ unsigned short f2bf(float f) {
  union { float f; unsigned u; } v; v.f = f;
  unsigned r = v.u + 0x7fffu + ((v.u >> 16) & 1u);
  return (unsigned short)(r >> 16);
}

__device__ __forceinline__ void gl_lds16(const void* g, void* l) {
  __builtin_amdgcn_global_load_lds(
      (const __attribute__((address_space(1))) unsigned int*)g,
      (__attribute__((address_space(3))) unsigned int*)l, 16, 0, 0);
}

// ---------------- f32 -> bf16 convert (grid-stride over n/4 float4s) ----------
__global__ __launch_bounds__(256) void cvt_bf16_k(const float* __restrict__ in,
                                                  unsigned short* __restrict__ out, int n4) {
  for (int i = blockIdx.x * 256 + threadIdx.x; i < n4; i += gridDim.x * 256) {
    float4 v = *(const float4*)&in[(size_t)i * 4];
    ushort4 o;
    o.x = f2bf(v.x); o.y = f2bf(v.y); o.z = f2bf(v.z); o.w = f2bf(v.w);
    *(ushort4*)&out[(size_t)i * 4] = o;
  }
}

// -------- conv weight transform: wreT[o][k*64+i] = conv_w[o][i][k] (bf16) -----
__global__ __launch_bounds__(256) void wret_k(const float* __restrict__ cw,
                                              unsigned short* __restrict__ out) {
  int idx = blockIdx.x * 256 + threadIdx.x;   // 2048*256 total
  int o = idx >> 8, q = idx & 255;
  int k = q >> 6, i = q & 63;
  out[idx] = f2bf(cw[o * 256 + i * 4 + k]);
}

// ---- scan weight prep: bw[h][m][t] = bf16(A_w[h][m][pi(t)]) ------------------
// pi(t) = 4*kg + dd + 32*kt + 16*eps, t = 32*kt + 8*kg + 2*dd + eps
__global__ __launch_bounds__(256) void bwprep_k(const float* __restrict__ Aw,
                                                unsigned short* __restrict__ bw) {
  int idx = blockIdx.x * 256 + threadIdx.x;   // 32*64*64 = 131072
  int t = idx & 63;
  int pi = 4 * ((t >> 3) & 3) + ((t >> 1) & 3) + 32 * (t >> 5) + 16 * (t & 1);
  bw[idx] = f2bf(Aw[(size_t)(idx >> 6) * 64 + pi]);
}

// ---- C_w prep permuted to the packed states layout: sigma(m) -----------------
// m=2p+eps: p<16 -> p+16*eps ; p>=16 -> p+16+16*eps
__global__ __launch_bounds__(256) void cwprep_k(const float* __restrict__ Cw,
                                                unsigned short* __restrict__ cwb) {
  int idx = blockIdx.x * 256 + threadIdx.x;   // 32*64*64
  int m = idx & 63;
  int p = m >> 1, e = m & 1;
  int sg = (p < 16) ? (p + 16 * e) : (p + 16 + 16 * e);
  cwb[idx] = f2bf(Cw[(size_t)(idx >> 6) * 64 + sg]);
}

// ---------------- GEMM: OUT[m][n] = sum_k X[m][k]*W[n][k], bf16 MFMA ----------
template <int SILU>
__global__ __launch_bounds__(256) void gemm_xwt_k(const unsigned short* __restrict__ X,
                                                  const unsigned short* __restrict__ W,
                                                  float* __restrict__ OUT,
                                                  int M, int N, int K) {
  __shared__ __align__(16) unsigned short As[128 * 32];
  __shared__ __align__(16) unsigned short Bs[128 * 32];
  const int tid = threadIdx.x, lane = tid & 63, wid = tid >> 6;
  const int wm = wid >> 1, wn = wid & 1;
  // XCD-aware bijective swizzle of the flattened block id (nwg % 8 == 0)
  const int lin = blockIdx.y * gridDim.x + blockIdx.x;
  const int cpx = (gridDim.x * gridDim.y) >> 3;
  const int swz = (lin & 7) * cpx + (lin >> 3);
  const int m0 = (swz % gridDim.x) * 128, n0 = (swz / gridDim.x) * 128;
  const int fr = lane & 15, kg = lane >> 4;
  const int sr = lane >> 2, sc = (lane & 3) * 8;   // staging: 4 lanes per row
  f32x4 acc[4][4] = {};
  for (int k0 = 0; k0 < K; k0 += 32) {
    const int cA0 = wid * 16, cA1 = (wid + 4) * 16;   // 16-row chunks per wave-call
    gl_lds16(&X[(size_t)(m0 + cA0 + sr) * K + k0 + sc], &As[cA0 * 32]);
    gl_lds16(&X[(size_t)(m0 + cA1 + sr) * K + k0 + sc], &As[cA1 * 32]);
    gl_lds16(&W[(size_t)(n0 + cA0 + sr) * K + k0 + sc], &Bs[cA0 * 32]);
    gl_lds16(&W[(size_t)(n0 + cA1 + sr) * K + k0 + sc], &Bs[cA1 * 32]);
    __syncthreads();
    bf16x8 af[4], bfr[4];
#pragma unroll
    for (int t = 0; t < 4; ++t) {
      af[t]  = *(const bf16x8*)&As[(wm * 64 + t * 16 + fr) * 32 + kg * 8];
      bfr[t] = *(const bf16x8*)&Bs[(wn * 64 + t * 16 + fr) * 32 + kg * 8];
    }
#pragma unroll
    for (int mt = 0; mt < 4; ++mt)
#pragma unroll
      for (int nt = 0; nt < 4; ++nt)
        acc[mt][nt] = __builtin_amdgcn_mfma_f32_16x16x32_bf16(af[mt], bfr[nt], acc[mt][nt], 0, 0, 0);
    __syncthreads();
  }
#pragma unroll
  for (int mt = 0; mt < 4; ++mt)
#pragma unroll
    for (int nt = 0; nt < 4; ++nt) {
      const int col = n0 + wn * 64 + nt * 16 + fr;
#pragma unroll
      for (int r = 0; r < 4; ++r) {
        const int row = m0 + wm * 64 + mt * 16 + kg * 4 + r;
        float v = acc[mt][nt][r];
        if (SILU) v = v / (1.f + __expf(-v));
        OUT[(size_t)row * N + col] = v;
      }
    }
}

// ------- grouped causal conv as MFMA GEMM; epilogue: (Bc+bias)*dt -> dB -------
__global__ __launch_bounds__(256) void conv_k(const unsigned short* __restrict__ xb,
                                              const unsigned short* __restrict__ wreT,
                                              const float* __restrict__ conv_b,
                                              const float* __restrict__ dt,
                                              float* __restrict__ dB) {
  __shared__ __align__(16) unsigned short x_lds[67 * 64];
  const int l0 = blockIdx.x * 64, g = blockIdx.y, b = blockIdx.z;
  const int tid = threadIdx.x, lane = tid & 63, wid = tid >> 6;
  {
    const int r = tid >> 3, ch = (tid & 7) * 8;
#pragma unroll
    for (int pass = 0; pass < 3; ++pass) {
      int rr = r + pass * 32;
      if (rr < 67) {
        int lg = l0 - 3 + rr;
        bf16x8 v = {};
        if (lg >= 0) v = *(const bf16x8*)&xb[(size_t)(b * L_SEQ + lg) * HIDN + g * 64 + ch];
        *(bf16x8*)&x_lds[rr * 64 + ch] = v;
      }
    }
  }
  __syncthreads();
  const int fr = lane & 15, kg = lane >> 4, wm = wid;
  f32x4 acc[4] = {};
#pragma unroll
  for (int ks = 0; ks < 8; ++ks) {
    bf16x8 a = *(const bf16x8*)&x_lds[(wm * 16 + fr + (ks >> 1)) * 64 + (ks & 1) * 32 + kg * 8];
#pragma unroll
    for (int nt = 0; nt < 4; ++nt) {
      bf16x8 bq = *(const bf16x8*)&wreT[(size_t)(g * 64 + nt * 16 + fr) * 256 + ks * 32 + kg * 8];
      acc[nt] = __builtin_amdgcn_mfma_f32_16x16x32_bf16(a, bq, acc[nt], 0, 0, 0);
    }
  }
#pragma unroll
  for (int nt = 0; nt < 4; ++nt) {
    const int o = nt * 16 + fr;
    const float bias = conv_b[g * 64 + o];
#pragma unroll
    for (int r = 0; r < 4; ++r) {
      const int lg = l0 + wm * 16 + kg * 4 + r;
      const float dtv = dt[b * L_SEQ + lg];
      dB[((size_t)(b * NH + g) * L_SEQ + lg) * 64 + o] = (acc[nt][r] + bias) * dtv;
    }
  }
}

// ------- selective scan v5: one wave/(b,h); s in A-operand, A_w in B-operand --
// Lane (c=lane&15, kg=lane>>4) owns S_q = s[c+16q] (f32). Step:
//   8 bpermute of packed prev-state dwords -> A-frag; 8 MFMA (2-dep chain);
//   acc_q reg0 = dot[c+16q] directly (D rows replicated; no export tree);
//   4x exp2 + fma; 2x cvt_pk -> carried packed dwords; kg==0 stores them.
// Weight B-frags precomputed with K-permutation pi (bwprep_k); states stored in
// packed order sigma (cwprep_k permutes C_w to match).
__global__ __launch_bounds__(64) void scan_k(const float* __restrict__ dB,
                                             const unsigned short* __restrict__ bw,
                                             const float* __restrict__ dt,
                                             unsigned int* __restrict__ st32) {
  const int bid = blockIdx.x;          // b*32 + h
  const int h = bid & 31, b = bid >> 5;
  const int lane = threadIdx.x;
  const int c = lane & 15, kg = lane >> 4;

  bf16x8 bwf[4][2];
  const unsigned short* bh = bw + (size_t)h * 4096;
#pragma unroll
  for (int nt = 0; nt < 4; ++nt)
#pragma unroll
    for (int kt = 0; kt < 2; ++kt)
      bwf[nt][kt] = *(const bf16x8*)&bh[(size_t)(nt * 16 + c) * 64 + kt * 32 + kg * 8];

  int bpa[4];
#pragma unroll
  for (int dd = 0; dd < 4; ++dd)
    bpa[dd] = (((lane & 48) | (kg * 4 + dd)) << 2);

  const float* dBp = dB + (size_t)bid * L_SEQ * 64 + c;
  unsigned int* stp = st32 + (size_t)bid * L_SEQ * 32;
  const float* dtp = dt + b * L_SEQ;

  float rA[16], rB[16];
#pragma unroll
  for (int u = 0; u < 4; ++u)
#pragma unroll
    for (int q = 0; q < 4; ++q) {
      rA[u * 4 + q] = dBp[(size_t)u * 64 + 16 * q];
      rB[u * 4 + q] = dBp[(size_t)(4 + u) * 64 + 16 * q];
    }
  float4 dtc = *(const float4*)&dtp[0];
  float4 dtn = *(const float4*)&dtp[4];

  float S0 = 0.f, S1 = 0.f, S2 = 0.f, S3 = 0.f;
  unsigned d0 = 0, d1 = 0;   // packed prev state: (s[c],s[c+16]) / (s[c+32],s[c+48])
  for (int g = 0; g < L_SEQ / 4; ++g) {
    const int l0 = g * 4;
    const int lp = (l0 + 8 <= L_SEQ - 4) ? (l0 + 8) : (L_SEQ - 4);
    float rn[16];
#pragma unroll
    for (int u = 0; u < 4; ++u)
#pragma unroll
      for (int q = 0; q < 4; ++q)
        rn[u * 4 + q] = dBp[(size_t)(lp + u) * 64 + 16 * q];
    float4 dtn2 = *(const float4*)&dtp[lp];
    float dtv[4] = { dtc.x * 1.44269504f, dtc.y * 1.44269504f,
                     dtc.z * 1.44269504f, dtc.w * 1.44269504f };
#pragma unroll
    for (int u = 0; u < 4; ++u) {
      union { bf16x8 v; unsigned u32[4]; } af0, af1;
#pragma unroll
      for (int dd = 0; dd < 4; ++dd)
        af0.u32[dd] = (unsigned)__builtin_amdgcn_ds_bpermute(bpa[dd], (int)d0);
#pragma unroll
      for (int dd = 0; dd < 4; ++dd)
        af1.u32[dd] = (unsigned)__builtin_amdgcn_ds_bpermute(bpa[dd], (int)d1);
      f32x4 z = {0.f, 0.f, 0.f, 0.f};
      f32x4 a0 = __builtin_amdgcn_mfma_f32_16x16x32_bf16(af0.v, bwf[0][0], z, 0, 0, 0);
      f32x4 a1 = __builtin_amdgcn_mfma_f32_16x16x32_bf16(af0.v, bwf[1][0], z, 0, 0, 0);
      f32x4 a2 = __builtin_amdgcn_mfma_f32_16x16x32_bf16(af0.v, bwf[2][0], z, 0, 0, 0);
      f32x4 a3 = __builtin_amdgcn_mfma_f32_16x16x32_bf16(af0.v, bwf[3][0], z, 0, 0, 0);
      a0 = __builtin_amdgcn_mfma_f32_16x16x32_bf16(af1.v, bwf[0][1], a0, 0, 0, 0);
      a1 = __builtin_amdgcn_mfma_f32_16x16x32_bf16(af1.v, bwf[1][1], a1, 0, 0, 0);
      a2 = __builtin_amdgcn_mfma_f32_16x16x32_bf16(af1.v, bwf[2][1], a2, 0, 0, 0);
      a3 = __builtin_amdgcn_mfma_f32_16x16x32_bf16(af1.v, bwf[3][1], a3, 0, 0, 0);
      const float e0 = __builtin_amdgcn_exp2f(a0[0] * dtv[u]);
      const float e1 = __builtin_amdgcn_exp2f(a1[0] * dtv[u]);
      const float e2 = __builtin_amdgcn_exp2f(a2[0] * dtv[u]);
      const float e3 = __builtin_amdgcn_exp2f(a3[0] * dtv[u]);
      S0 = e0 * S0 + rA[u * 4 + 0];
      S1 = e1 * S1 + rA[u * 4 + 1];
      S2 = e2 * S2 + rA[u * 4 + 2];
      S3 = e3 * S3 + rA[u * 4 + 3];
      asm("v_cvt_pk_bf16_f32 %0, %1, %2" : "=v"(d0) : "v"(S0), "v"(S1));
      asm("v_cvt_pk_bf16_f32 %0, %1, %2" : "=v"(d1) : "v"(S2), "v"(S3));
      if (kg == 0) {
        stp[(size_t)(l0 + u) * 32 + c] = d0;
        stp[(size_t)(l0 + u) * 32 + 16 + c] = d1;
      }
    }
#pragma unroll
    for (int i = 0; i < 16; ++i) { rA[i] = rB[i]; rB[i] = rn[i]; }
    dtc = dtn; dtn = dtn2;
  }
}

// ----- C projection + x*D + silu(gate) multiply; writes hs1 (b,l,hid) f32 -----
__global__ __launch_bounds__(256) void proj_k(const unsigned short* __restrict__ st,
                                              const unsigned short* __restrict__ cwb,
                                              const float* __restrict__ xin,
                                              const float* __restrict__ Dp,
                                              const float* __restrict__ gs,
                                              float* __restrict__ hs1) {
  const int l0 = blockIdx.x * 64, h = blockIdx.y, b = blockIdx.z;
  const int tid = threadIdx.x, lane = tid & 63, wid = tid >> 6;
  const int fr = lane & 15, kg = lane >> 4, wm = wid;
  f32x4 acc[4] = {};
#pragma unroll
  for (int ks = 0; ks < 2; ++ks) {
    bf16x8 a = *(const bf16x8*)&st[((size_t)(b * NH + h) * L_SEQ + l0 + wm * 16 + fr) * 64 + ks * 32 + kg * 8];
#pragma unroll
    for (int nt = 0; nt < 4; ++nt) {
      bf16x8 bq = *(const bf16x8*)&cwb[(size_t)(h * 64 + nt * 16 + fr) * 64 + ks * 32 + kg * 8];
      acc[nt] = __builtin_amdgcn_mfma_f32_16x16x32_bf16(a, bq, acc[nt], 0, 0, 0);
    }
  }
  const float Dh = Dp[h];
#pragma unroll
  for (int nt = 0; nt < 4; ++nt) {
    const int ccol = h * 64 + nt * 16 + fr;
#pragma unroll
    for (int r = 0; r < 4; ++r) {
      const int lg = l0 + wm * 16 + kg * 4 + r;
      const size_t idx = (size_t)(b * L_SEQ + lg) * HIDN + ccol;
      float v = acc[nt][r] + xin[idx] * Dh;
      hs1[idx] = v * gs[idx];
    }
  }
}

// --------------------- gated RMSNorm -> bf16 rows -----------------------------
__global__ __launch_bounds__(256) void norm_k(const float* __restrict__ hs1,
                                              const float* __restrict__ nw,
                                              unsigned short* __restrict__ out) {
  const int row = blockIdx.x;
  const float* p = hs1 + (size_t)row * HIDN;
  const int c0 = threadIdx.x * 8;
  float4 u0 = *(const float4*)&p[c0];
  float4 u1 = *(const float4*)&p[c0 + 4];
  float ss = u0.x * u0.x + u0.y * u0.y + u0.z * u0.z + u0.w * u0.w +
             u1.x * u1.x + u1.y * u1.y + u1.z * u1.z + u1.w * u1.w;
#pragma unroll
  for (int off = 32; off; off >>= 1) ss += __shfl_xor(ss, off);
  __shared__ float pr[4];
  if ((threadIdx.x & 63) == 0) pr[threadIdx.x >> 6] = ss;
  __syncthreads();
  float tot = pr[0] + pr[1] + pr[2] + pr[3];
  float rs = rsqrtf(tot * (1.f / HIDN) + 1e-6f);
  bf16x8 res;
  res[0] = (short)f2bf(nw[c0 + 0] * u0.x * rs);
  res[1] = (short)f2bf(nw[c0 + 1] * u0.y * rs);
  res[2] = (short)f2bf(nw[c0 + 2] * u0.z * rs);
  res[3] = (short)f2bf(nw[c0 + 3] * u0.w * rs);
  res[4] = (short)f2bf(nw[c0 + 4] * u1.x * rs);
  res[5] = (short)f2bf(nw[c0 + 5] * u1.y * rs);
  res[6] = (short)f2bf(nw[c0 + 6] * u1.z * rs);
  res[7] = (short)f2bf(nw[c0 + 7] * u1.w * rs);
  *(bf16x8*)&out[(size_t)row * HIDN + c0] = res;
}

extern "C" void kernel_launch(void* const* d_in, const int* in_sizes, int n_in,
                              void* d_out, int out_size, void* d_ws, size_t ws_size,
                              hipStream_t stream) {
  const float* x  = (const float*)d_in[0];
  const float* dt = (const float*)d_in[1];
  const float* gw = (const float*)d_in[2];
  const float* Aw = (const float*)d_in[3];
  const float* cw = (const float*)d_in[4];
  const float* cb = (const float*)d_in[5];
  const float* Cw = (const float*)d_in[6];
  const float* Dp = (const float*)d_in[7];
  const float* nw = (const float*)d_in[8];
  const float* ow = (const float*)d_in[9];
  float* out = (float*)d_out;

  // workspace layout (bytes); x_bf16 region is reused for states after conv.
  char* w = (char*)d_ws;
  unsigned short* xb   = (unsigned short*)(w);                // 32MB
  unsigned short* stb  = (unsigned short*)(w);                // overlay (after conv)
  unsigned short* gwb  = (unsigned short*)(w + 33554432);     // 8MB
  unsigned short* owb  = (unsigned short*)(w + 41943040);     // 8MB
  unsigned short* wret = (unsigned short*)(w + 50331648);     // 1MB
  unsigned short* cwb  = (unsigned short*)(w + 51380224);     // 256KB
  unsigned short* bw   = (unsigned short*)(w + 51642368);     // 256KB
  float*          dBf  = (float*)(w + 52428800);              // 64MB
  float*          hs1  = dBf;                                 // overlay (after scan)
  unsigned short* hsb  = (unsigned short*)(w + 119537664);    // 32MB
  if (ws_size < 153092096) return;

  cvt_bf16_k<<<2048, 256, 0, stream>>>(x, xb, 16777216 / 4);
  cvt_bf16_k<<<1024, 256, 0, stream>>>(gw, gwb, 4194304 / 4);
  cvt_bf16_k<<<1024, 256, 0, stream>>>(ow, owb, 4194304 / 4);
  cwprep_k<<<512, 256, 0, stream>>>(Cw, cwb);
  bwprep_k<<<512, 256, 0, stream>>>(Aw, bw);
  wret_k<<<2048, 256, 0, stream>>>(cw, wret);

  dim3 gg(8192 / 128, 2048 / 128);
  gemm_xwt_k<1><<<gg, 256, 0, stream>>>(xb, gwb, out, 8192, 2048, 2048);  // silu(gate) -> d_out
  conv_k<<<dim3(32, 32, 4), 256, 0, stream>>>(xb, wret, cb, dt, dBf);
  scan_k<<<128, 64, 0, stream>>>(dBf, bw, dt, (unsigned int*)stb);
  proj_k<<<dim3(32, 32, 4), 256, 0, stream>>>(stb, cwb, x, Dp, out, hs1);
  norm_k<<<8192, 256, 0, stream>>>(hs1, nw, hsb);
  gemm_xwt_k<0><<<gg, 256, 0, stream>>>(hsb, owb, out, 8192, 2048, 2048);
}

// Round 8
// 807.658 us; speedup vs baseline: 1.2007x; 1.0932x over previous
//
#include <hip/hip_runtime.h>
#include <hip/hip_bf16.h>

#define L_SEQ 2048
#define HIDN  2048
#define NH    32
#define BATCHN 4

using bf16x8 = __attribute__((ext_vector_type(8))) short;
using f32x4  = __attribute__((ext_vector_type(4))) float;
using half2v = __attribute__((ext_vector_type(2))) _Float16;

__device__ __forceinline__ unsigned short f2bf(float f) {
  union { float f; unsigned u; } v; v.f = f;
  unsigned r = v.u + 0x7fffu + ((v.u >> 16) & 1u);
  return (unsigned short)(r >> 16);
}

__device__ __forceinline__ void gl_lds16(const void* g, void* l) {
  __builtin_amdgcn_global_load_lds(
      (const __attribute__((address_space(1))) unsigned int*)g,
      (__attribute__((address_space(3))) unsigned int*)l, 16, 0, 0);
}

__device__ __forceinline__ half2v pkrtz(float lo, float hi) {
  return __builtin_bit_cast(half2v, __builtin_amdgcn_cvt_pkrtz(lo, hi));
}

template <int CTRL>
__device__ __forceinline__ float qperm(float x) {
  int xi = __builtin_bit_cast(int, x);
  int yi = __builtin_amdgcn_update_dpp(0, xi, CTRL, 0xF, 0xF, true);
  return __builtin_bit_cast(float, yi);
}

// ---------------- f32 -> bf16 convert (grid-stride over n/4 float4s) ----------
__global__ __launch_bounds__(256) void cvt_bf16_k(const float* __restrict__ in,
                                                  unsigned short* __restrict__ out, int n4) {
  for (int i = blockIdx.x * 256 + threadIdx.x; i < n4; i += gridDim.x * 256) {
    float4 v = *(const float4*)&in[(size_t)i * 4];
    ushort4 o;
    o.x = f2bf(v.x); o.y = f2bf(v.y); o.z = f2bf(v.z); o.w = f2bf(v.w);
    *(ushort4*)&out[(size_t)i * 4] = o;
  }
}

// -------- conv weight transform: wreT[o][k*64+i] = conv_w[o][i][k] (bf16) -----
__global__ __launch_bounds__(256) void wret_k(const float* __restrict__ cw,
                                              unsigned short* __restrict__ out) {
  int idx = blockIdx.x * 256 + threadIdx.x;   // 2048*256 total
  int o = idx >> 8, q = idx & 255;
  int k = q >> 6, i = q & 63;
  out[idx] = f2bf(cw[o * 256 + i * 4 + k]);
}

// ---------------- GEMM: OUT[m][n] = sum_k X[m][k]*W[n][k], bf16 MFMA ----------
template <int SILU>
__global__ __launch_bounds__(256) void gemm_xwt_k(const unsigned short* __restrict__ X,
                                                  const unsigned short* __restrict__ W,
                                                  float* __restrict__ OUT,
                                                  int M, int N, int K) {
  __shared__ __align__(16) unsigned short As[128 * 32];
  __shared__ __align__(16) unsigned short Bs[128 * 32];
  const int tid = threadIdx.x, lane = tid & 63, wid = tid >> 6;
  const int wm = wid >> 1, wn = wid & 1;
  // XCD-aware bijective swizzle of the flattened block id (nwg % 8 == 0)
  const int lin = blockIdx.y * gridDim.x + blockIdx.x;
  const int cpx = (gridDim.x * gridDim.y) >> 3;
  const int swz = (lin & 7) * cpx + (lin >> 3);
  const int m0 = (swz % gridDim.x) * 128, n0 = (swz / gridDim.x) * 128;
  const int fr = lane & 15, kg = lane >> 4;
  const int sr = lane >> 2, sc = (lane & 3) * 8;   // staging: 4 lanes per row
  f32x4 acc[4][4] = {};
  for (int k0 = 0; k0 < K; k0 += 32) {
    const int cA0 = wid * 16, cA1 = (wid + 4) * 16;   // 16-row chunks per wave-call
    gl_lds16(&X[(size_t)(m0 + cA0 + sr) * K + k0 + sc], &As[cA0 * 32]);
    gl_lds16(&X[(size_t)(m0 + cA1 + sr) * K + k0 + sc], &As[cA1 * 32]);
    gl_lds16(&W[(size_t)(n0 + cA0 + sr) * K + k0 + sc], &Bs[cA0 * 32]);
    gl_lds16(&W[(size_t)(n0 + cA1 + sr) * K + k0 + sc], &Bs[cA1 * 32]);
    __syncthreads();
    bf16x8 af[4], bfr[4];
#pragma unroll
    for (int t = 0; t < 4; ++t) {
      af[t]  = *(const bf16x8*)&As[(wm * 64 + t * 16 + fr) * 32 + kg * 8];
      bfr[t] = *(const bf16x8*)&Bs[(wn * 64 + t * 16 + fr) * 32 + kg * 8];
    }
#pragma unroll
    for (int mt = 0; mt < 4; ++mt)
#pragma unroll
      for (int nt = 0; nt < 4; ++nt)
        acc[mt][nt] = __builtin_amdgcn_mfma_f32_16x16x32_bf16(af[mt], bfr[nt], acc[mt][nt], 0, 0, 0);
    __syncthreads();
  }
#pragma unroll
  for (int mt = 0; mt < 4; ++mt)
#pragma unroll
    for (int nt = 0; nt < 4; ++nt) {
      const int col = n0 + wn * 64 + nt * 16 + fr;
#pragma unroll
      for (int r = 0; r < 4; ++r) {
        const int row = m0 + wm * 64 + mt * 16 + kg * 4 + r;
        float v = acc[mt][nt][r];
        if (SILU) v = v / (1.f + __expf(-v));
        OUT[(size_t)row * N + col] = v;
      }
    }
}

// ------- grouped causal conv as MFMA GEMM; epilogue: (Bc+bias)*dt -> dB -------
__global__ __launch_bounds__(256) void conv_k(const unsigned short* __restrict__ xb,
                                              const unsigned short* __restrict__ wreT,
                                              const float* __restrict__ conv_b,
                                              const float* __restrict__ dt,
                                              float* __restrict__ dB) {
  __shared__ __align__(16) unsigned short x_lds[67 * 64];
  const int l0 = blockIdx.x * 64, g = blockIdx.y, b = blockIdx.z;
  const int tid = threadIdx.x, lane = tid & 63, wid = tid >> 6;
  {
    const int r = tid >> 3, ch = (tid & 7) * 8;
#pragma unroll
    for (int pass = 0; pass < 3; ++pass) {
      int rr = r + pass * 32;
      if (rr < 67) {
        int lg = l0 - 3 + rr;
        bf16x8 v = {};
        if (lg >= 0) v = *(const bf16x8*)&xb[(size_t)(b * L_SEQ + lg) * HIDN + g * 64 + ch];
        *(bf16x8*)&x_lds[rr * 64 + ch] = v;
      }
    }
  }
  __syncthreads();
  const int fr = lane & 15, kg = lane >> 4, wm = wid;
  f32x4 acc[4] = {};
#pragma unroll
  for (int ks = 0; ks < 8; ++ks) {
    bf16x8 a = *(const bf16x8*)&x_lds[(wm * 16 + fr + (ks >> 1)) * 64 + (ks & 1) * 32 + kg * 8];
#pragma unroll
    for (int nt = 0; nt < 4; ++nt) {
      bf16x8 bq = *(const bf16x8*)&wreT[(size_t)(g * 64 + nt * 16 + fr) * 256 + ks * 32 + kg * 8];
      acc[nt] = __builtin_amdgcn_mfma_f32_16x16x32_bf16(a, bq, acc[nt], 0, 0, 0);
    }
  }
#pragma unroll
  for (int nt = 0; nt < 4; ++nt) {
    const int o = nt * 16 + fr;
    const float bias = conv_b[g * 64 + o];
#pragma unroll
    for (int r = 0; r < 4; ++r) {
      const int lg = l0 + wm * 16 + kg * 4 + r;
      const float dtv = dt[b * L_SEQ + lg];
      dB[((size_t)(b * NH + g) * L_SEQ + lg) * 64 + o] = (acc[nt][r] + bias) * dtv;
    }
  }
}

// ------- selective scan v6: one wave/(b,h), pure VALU (no MFMA on chain) ------
// Lane m owns A-row m (32 half2 dwords, f16) and state s[m] (f32). Per step:
//   DPP quad-swap + 2 cndmask + cvt_pkrtz -> pair dword (s[2p],s[2p+1]);
//   32 broadcast ds_bpermute (conflict-free) replicate all pairs to all lanes;
//   32 fdot2 in 4 independent 8-deep chains; tree add; Taylor exp (|x|<~0.02);
//   fma. MFMA's XDL latency + acc->VALU readback are gone from the chain.
__global__ __launch_bounds__(64) void scan_k(const float* __restrict__ dB,
                                             const float* __restrict__ Aw,
                                             const float* __restrict__ dt,
                                             unsigned short* __restrict__ states) {
  const int bid = blockIdx.x;          // b*32 + h
  const int h = bid & 31, b = bid >> 5;
  const int lane = threadIdx.x;

  half2v aw[32];
  const float* Ar = Aw + (size_t)(h * 64 + lane) * 64;
#pragma unroll
  for (int j4 = 0; j4 < 16; ++j4) {
    float4 v = *(const float4*)&Ar[j4 * 4];
    aw[2 * j4]     = pkrtz(v.x, v.y);
    aw[2 * j4 + 1] = pkrtz(v.z, v.w);
  }
  int bpa[32];
#pragma unroll
  for (int p = 0; p < 32; ++p) bpa[p] = p * 8;   // byte addr of lane 2p

  const float* dBp = dB + (size_t)bid * L_SEQ * 64 + lane;
  unsigned short* stp = states + (size_t)bid * L_SEQ * 64 + lane;
  const float* dtp = dt + b * L_SEQ;

  float r0[4], r1[4];
#pragma unroll
  for (int u = 0; u < 4; ++u) r0[u] = dBp[(size_t)u * 64];
#pragma unroll
  for (int u = 0; u < 4; ++u) r1[u] = dBp[(size_t)(4 + u) * 64];
  float4 dtc = *(const float4*)&dtp[0];
  float4 dtn = *(const float4*)&dtp[4];

  float s = 0.f;
  for (int g = 0; g < L_SEQ / 4; ++g) {
    const int l0 = g * 4;
    const int lp = (l0 + 8 <= L_SEQ - 4) ? (l0 + 8) : (L_SEQ - 4);
    float rn[4];
#pragma unroll
    for (int u = 0; u < 4; ++u) rn[u] = dBp[(size_t)(lp + u) * 64];
    float4 dtn2 = *(const float4*)&dtp[lp];
    const float dtu[4] = { dtc.x, dtc.y, dtc.z, dtc.w };
#pragma unroll
    for (int u = 0; u < 4; ++u) {
      // pair dword: lanes 2p and 2p+1 both build (s[2p], s[2p+1])
      float sn = qperm<0xB1>(s);
      float lo = (lane & 1) ? sn : s;
      float hi = (lane & 1) ? s : sn;
      half2v dp = pkrtz(lo, hi);
      int dbits = __builtin_bit_cast(int, dp);
      half2v w[32];
#pragma unroll
      for (int p = 0; p < 32; ++p)
        w[p] = __builtin_bit_cast(half2v, __builtin_amdgcn_ds_bpermute(bpa[p], dbits));
      float a0 = 0.f, a1 = 0.f, a2 = 0.f, a3 = 0.f;
#pragma unroll
      for (int j = 0; j < 8; ++j) {
        a0 = __builtin_amdgcn_fdot2(w[j],      aw[j],      a0, false);
        a1 = __builtin_amdgcn_fdot2(w[8 + j],  aw[8 + j],  a1, false);
        a2 = __builtin_amdgcn_fdot2(w[16 + j], aw[16 + j], a2, false);
        a3 = __builtin_amdgcn_fdot2(w[24 + j], aw[24 + j], a3, false);
      }
      const float dot = (a0 + a1) + (a2 + a3);
      const float x = dot * dtu[u];
      const float e = __builtin_fmaf(x * x, 0.5f, 1.f + x);   // exp(x), |x| tiny
      s = e * s + r0[u];
      stp[(size_t)(l0 + u) * 64] = f2bf(s);
    }
#pragma unroll
    for (int u = 0; u < 4; ++u) { r0[u] = r1[u]; r1[u] = rn[u]; }
    dtc = dtn; dtn = dtn2;
  }
}

// ----- C projection + x*D + silu(gate) multiply; writes hs1 (b,l,hid) f32 -----
__global__ __launch_bounds__(256) void proj_k(const unsigned short* __restrict__ st,
                                              const unsigned short* __restrict__ cwb,
                                              const float* __restrict__ xin,
                                              const float* __restrict__ Dp,
                                              const float* __restrict__ gs,
                                              float* __restrict__ hs1) {
  const int l0 = blockIdx.x * 64, h = blockIdx.y, b = blockIdx.z;
  const int tid = threadIdx.x, lane = tid & 63, wid = tid >> 6;
  const int fr = lane & 15, kg = lane >> 4, wm = wid;
  f32x4 acc[4] = {};
#pragma unroll
  for (int ks = 0; ks < 2; ++ks) {
    bf16x8 a = *(const bf16x8*)&st[((size_t)(b * NH + h) * L_SEQ + l0 + wm * 16 + fr) * 64 + ks * 32 + kg * 8];
#pragma unroll
    for (int nt = 0; nt < 4; ++nt) {
      bf16x8 bq = *(const bf16x8*)&cwb[(size_t)(h * 64 + nt * 16 + fr) * 64 + ks * 32 + kg * 8];
      acc[nt] = __builtin_amdgcn_mfma_f32_16x16x32_bf16(a, bq, acc[nt], 0, 0, 0);
    }
  }
  const float Dh = Dp[h];
#pragma unroll
  for (int nt = 0; nt < 4; ++nt) {
    const int ccol = h * 64 + nt * 16 + fr;
#pragma unroll
    for (int r = 0; r < 4; ++r) {
      const int lg = l0 + wm * 16 + kg * 4 + r;
      const size_t idx = (size_t)(b * L_SEQ + lg) * HIDN + ccol;
      float v = acc[nt][r] + xin[idx] * Dh;
      hs1[idx] = v * gs[idx];
    }
  }
}

// --------------------- gated RMSNorm -> bf16 rows -----------------------------
__global__ __launch_bounds__(256) void norm_k(const float* __restrict__ hs1,
                                              const float* __restrict__ nw,
                                              unsigned short* __restrict__ out) {
  const int row = blockIdx.x;
  const float* p = hs1 + (size_t)row * HIDN;
  const int c0 = threadIdx.x * 8;
  float4 u0 = *(const float4*)&p[c0];
  float4 u1 = *(const float4*)&p[c0 + 4];
  float ss = u0.x * u0.x + u0.y * u0.y + u0.z * u0.z + u0.w * u0.w +
             u1.x * u1.x + u1.y * u1.y + u1.z * u1.z + u1.w * u1.w;
#pragma unroll
  for (int off = 32; off; off >>= 1) ss += __shfl_xor(ss, off);
  __shared__ float pr[4];
  if ((threadIdx.x & 63) == 0) pr[threadIdx.x >> 6] = ss;
  __syncthreads();
  float tot = pr[0] + pr[1] + pr[2] + pr[3];
  float rs = rsqrtf(tot * (1.f / HIDN) + 1e-6f);
  bf16x8 res;
  res[0] = (short)f2bf(nw[c0 + 0] * u0.x * rs);
  res[1] = (short)f2bf(nw[c0 + 1] * u0.y * rs);
  res[2] = (short)f2bf(nw[c0 + 2] * u0.z * rs);
  res[3] = (short)f2bf(nw[c0 + 3] * u0.w * rs);
  res[4] = (short)f2bf(nw[c0 + 4] * u1.x * rs);
  res[5] = (short)f2bf(nw[c0 + 5] * u1.y * rs);
  res[6] = (short)f2bf(nw[c0 + 6] * u1.z * rs);
  res[7] = (short)f2bf(nw[c0 + 7] * u1.w * rs);
  *(bf16x8*)&out[(size_t)row * HIDN + c0] = res;
}

extern "C" void kernel_launch(void* const* d_in, const int* in_sizes, int n_in,
                              void* d_out, int out_size, void* d_ws, size_t ws_size,
                              hipStream_t stream) {
  const float* x  = (const float*)d_in[0];
  const float* dt = (const float*)d_in[1];
  const float* gw = (const float*)d_in[2];
  const float* Aw = (const float*)d_in[3];
  const float* cw = (const float*)d_in[4];
  const float* cb = (const float*)d_in[5];
  const float* Cw = (const float*)d_in[6];
  const float* Dp = (const float*)d_in[7];
  const float* nw = (const float*)d_in[8];
  const float* ow = (const float*)d_in[9];
  float* out = (float*)d_out;

  // workspace layout (bytes); x_bf16 region is reused for states after conv.
  char* w = (char*)d_ws;
  unsigned short* xb   = (unsigned short*)(w);                // 32MB
  unsigned short* stb  = (unsigned short*)(w);                // overlay (after conv)
  unsigned short* gwb  = (unsigned short*)(w + 33554432);     // 8MB
  unsigned short* owb  = (unsigned short*)(w + 41943040);     // 8MB
  unsigned short* wret = (unsigned short*)(w + 50331648);     // 1MB
  unsigned short* cwb  = (unsigned short*)(w + 51380224);     // 256KB
  float*          dBf  = (float*)(w + 52428800);              // 64MB
  float*          hs1  = dBf;                                 // overlay (after scan)
  unsigned short* hsb  = (unsigned short*)(w + 119537664);    // 32MB
  if (ws_size < 153092096) return;

  cvt_bf16_k<<<2048, 256, 0, stream>>>(x, xb, 16777216 / 4);
  cvt_bf16_k<<<1024, 256, 0, stream>>>(gw, gwb, 4194304 / 4);
  cvt_bf16_k<<<1024, 256, 0, stream>>>(ow, owb, 4194304 / 4);
  cvt_bf16_k<<<128, 256, 0, stream>>>(Cw, cwb, 131072 / 4);
  wret_k<<<2048, 256, 0, stream>>>(cw, wret);

  dim3 gg(8192 / 128, 2048 / 128);
  gemm_xwt_k<1><<<gg, 256, 0, stream>>>(xb, gwb, out, 8192, 2048, 2048);  // silu(gate) -> d_out
  conv_k<<<dim3(32, 32, 4), 256, 0, stream>>>(xb, wret, cb, dt, dBf);
  scan_k<<<128, 64, 0, stream>>>(dBf, Aw, dt, stb);
  proj_k<<<dim3(32, 32, 4), 256, 0, stream>>>(stb, cwb, x, Dp, out, hs1);
  norm_k<<<8192, 256, 0, stream>>>(hs1, nw, hsb);
  gemm_xwt_k<0><<<gg, 256, 0, stream>>>(hsb, owb, out, 8192, 2048, 2048);
}

// Round 9
// 698.525 us; speedup vs baseline: 1.3883x; 1.1562x over previous
//
#include <hip/hip_runtime.h>
#include <hip/hip_bf16.h>

#define L_SEQ 2048
#define HIDN  2048
#define NH    32
#define BATCHN 4

using bf16x8 = __attribute__((ext_vector_type(8))) short;
using f32x4  = __attribute__((ext_vector_type(4))) float;
using half2v = __attribute__((ext_vector_type(2))) _Float16;

__device__ __forceinline__ unsigned short f2bf(float f) {
  union { float f; unsigned u; } v; v.f = f;
  unsigned r = v.u + 0x7fffu + ((v.u >> 16) & 1u);
  return (unsigned short)(r >> 16);
}

__device__ __forceinline__ void gl_lds16(const void* g, void* l) {
  __builtin_amdgcn_global_load_lds(
      (const __attribute__((address_space(1))) unsigned int*)g,
      (__attribute__((address_space(3))) unsigned int*)l, 16, 0, 0);
}

__device__ __forceinline__ half2v pkrtz(float lo, float hi) {
  return __builtin_bit_cast(half2v, __builtin_amdgcn_cvt_pkrtz(lo, hi));
}

template <int CTRL>
__device__ __forceinline__ float qperm(float x) {
  int xi = __builtin_bit_cast(int, x);
  int yi = __builtin_amdgcn_update_dpp(0, xi, CTRL, 0xF, 0xF, true);
  return __builtin_bit_cast(float, yi);
}

// ---------------- f32 -> bf16 convert (grid-stride over n/4 float4s) ----------
__global__ __launch_bounds__(256) void cvt_bf16_k(const float* __restrict__ in,
                                                  unsigned short* __restrict__ out, int n4) {
  for (int i = blockIdx.x * 256 + threadIdx.x; i < n4; i += gridDim.x * 256) {
    float4 v = *(const float4*)&in[(size_t)i * 4];
    ushort4 o;
    o.x = f2bf(v.x); o.y = f2bf(v.y); o.z = f2bf(v.z); o.w = f2bf(v.w);
    *(ushort4*)&out[(size_t)i * 4] = o;
  }
}

// -------- conv weight transform: wreT[o][k*64+i] = conv_w[o][i][k] (bf16) -----
__global__ __launch_bounds__(256) void wret_k(const float* __restrict__ cw,
                                              unsigned short* __restrict__ out) {
  int idx = blockIdx.x * 256 + threadIdx.x;   // 2048*256 total
  int o = idx >> 8, q = idx & 255;
  int k = q >> 6, i = q & 63;
  out[idx] = f2bf(cw[o * 256 + i * 4 + k]);
}

// ---------------- GEMM: OUT[m][n] = sum_k X[m][k]*W[n][k], bf16 MFMA ----------
template <int SILU>
__global__ __launch_bounds__(256) void gemm_xwt_k(const unsigned short* __restrict__ X,
                                                  const unsigned short* __restrict__ W,
                                                  float* __restrict__ OUT,
                                                  int M, int N, int K) {
  __shared__ __align__(16) unsigned short As[128 * 32];
  __shared__ __align__(16) unsigned short Bs[128 * 32];
  const int tid = threadIdx.x, lane = tid & 63, wid = tid >> 6;
  const int wm = wid >> 1, wn = wid & 1;
  // XCD-aware bijective swizzle of the flattened block id (nwg % 8 == 0)
  const int lin = blockIdx.y * gridDim.x + blockIdx.x;
  const int cpx = (gridDim.x * gridDim.y) >> 3;
  const int swz = (lin & 7) * cpx + (lin >> 3);
  const int m0 = (swz % gridDim.x) * 128, n0 = (swz / gridDim.x) * 128;
  const int fr = lane & 15, kg = lane >> 4;
  const int sr = lane >> 2, sc = (lane & 3) * 8;   // staging: 4 lanes per row
  f32x4 acc[4][4] = {};
  for (int k0 = 0; k0 < K; k0 += 32) {
    const int cA0 = wid * 16, cA1 = (wid + 4) * 16;   // 16-row chunks per wave-call
    gl_lds16(&X[(size_t)(m0 + cA0 + sr) * K + k0 + sc], &As[cA0 * 32]);
    gl_lds16(&X[(size_t)(m0 + cA1 + sr) * K + k0 + sc], &As[cA1 * 32]);
    gl_lds16(&W[(size_t)(n0 + cA0 + sr) * K + k0 + sc], &Bs[cA0 * 32]);
    gl_lds16(&W[(size_t)(n0 + cA1 + sr) * K + k0 + sc], &Bs[cA1 * 32]);
    __syncthreads();
    bf16x8 af[4], bfr[4];
#pragma unroll
    for (int t = 0; t < 4; ++t) {
      af[t]  = *(const bf16x8*)&As[(wm * 64 + t * 16 + fr) * 32 + kg * 8];
      bfr[t] = *(const bf16x8*)&Bs[(wn * 64 + t * 16 + fr) * 32 + kg * 8];
    }
#pragma unroll
    for (int mt = 0; mt < 4; ++mt)
#pragma unroll
      for (int nt = 0; nt < 4; ++nt)
        acc[mt][nt] = __builtin_amdgcn_mfma_f32_16x16x32_bf16(af[mt], bfr[nt], acc[mt][nt], 0, 0, 0);
    __syncthreads();
  }
#pragma unroll
  for (int mt = 0; mt < 4; ++mt)
#pragma unroll
    for (int nt = 0; nt < 4; ++nt) {
      const int col = n0 + wn * 64 + nt * 16 + fr;
#pragma unroll
      for (int r = 0; r < 4; ++r) {
        const int row = m0 + wm * 64 + mt * 16 + kg * 4 + r;
        float v = acc[mt][nt][r];
        if (SILU) v = v / (1.f + __expf(-v));
        OUT[(size_t)row * N + col] = v;
      }
    }
}

// ------- grouped causal conv as MFMA GEMM; epilogue: (Bc+bias)*dt -> dB -------
__global__ __launch_bounds__(256) void conv_k(const unsigned short* __restrict__ xb,
                                              const unsigned short* __restrict__ wreT,
                                              const float* __restrict__ conv_b,
                                              const float* __restrict__ dt,
                                              float* __restrict__ dB) {
  __shared__ __align__(16) unsigned short x_lds[67 * 64];
  const int l0 = blockIdx.x * 64, g = blockIdx.y, b = blockIdx.z;
  const int tid = threadIdx.x, lane = tid & 63, wid = tid >> 6;
  {
    const int r = tid >> 3, ch = (tid & 7) * 8;
#pragma unroll
    for (int pass = 0; pass < 3; ++pass) {
      int rr = r + pass * 32;
      if (rr < 67) {
        int lg = l0 - 3 + rr;
        bf16x8 v = {};
        if (lg >= 0) v = *(const bf16x8*)&xb[(size_t)(b * L_SEQ + lg) * HIDN + g * 64 + ch];
        *(bf16x8*)&x_lds[rr * 64 + ch] = v;
      }
    }
  }
  __syncthreads();
  const int fr = lane & 15, kg = lane >> 4, wm = wid;
  f32x4 acc[4] = {};
#pragma unroll
  for (int ks = 0; ks < 8; ++ks) {
    bf16x8 a = *(const bf16x8*)&x_lds[(wm * 16 + fr + (ks >> 1)) * 64 + (ks & 1) * 32 + kg * 8];
#pragma unroll
    for (int nt = 0; nt < 4; ++nt) {
      bf16x8 bq = *(const bf16x8*)&wreT[(size_t)(g * 64 + nt * 16 + fr) * 256 + ks * 32 + kg * 8];
      acc[nt] = __builtin_amdgcn_mfma_f32_16x16x32_bf16(a, bq, acc[nt], 0, 0, 0);
    }
  }
#pragma unroll
  for (int nt = 0; nt < 4; ++nt) {
    const int o = nt * 16 + fr;
    const float bias = conv_b[g * 64 + o];
#pragma unroll
    for (int r = 0; r < 4; ++r) {
      const int lg = l0 + wm * 16 + kg * 4 + r;
      const float dtv = dt[b * L_SEQ + lg];
      dB[((size_t)(b * NH + g) * L_SEQ + lg) * 64 + o] = (acc[nt][r] + bias) * dtv;
    }
  }
}

// ---- FUSED: blocks 0..127 = selective scan (1 wave each); blocks 128..1151 ---
// ---- = gate GEMM (8192x2048x2048 + silu). GEMM hides under scan latency. -----
// Scan v7: exchange via 32 v_readlane -> SGPR (wave-uniform pair dwords), dots
// via v_dot2_f32_f16 with SGPR operand. No LDS, no DS ops on the chain.
__global__ __launch_bounds__(256) void scan_gemm_k(const float* __restrict__ dB,
                                                   const float* __restrict__ Aw,
                                                   const float* __restrict__ dt,
                                                   unsigned short* __restrict__ states,
                                                   const unsigned short* __restrict__ X,
                                                   const unsigned short* __restrict__ W,
                                                   float* __restrict__ OUT) {
  __shared__ __align__(16) unsigned short As[128 * 32];
  __shared__ __align__(16) unsigned short Bs[128 * 32];
  if (blockIdx.x >= 128) {
    // ----------------- gate GEMM tile (grid 64 x 16, swizzled) ---------------
    const int tid = threadIdx.x, lane = tid & 63, wid = tid >> 6;
    const int wm = wid >> 1, wn = wid & 1;
    const int gb = blockIdx.x - 128;              // 0..1023
    const int swz = (gb & 7) * 128 + (gb >> 3);   // XCD-bijective (1024 % 8 == 0)
    const int m0 = (swz & 63) * 128;
    const int n0 = (swz >> 6) * 128;
    const int fr = lane & 15, kg = lane >> 4;
    const int sr = lane >> 2, sc = (lane & 3) * 8;
    f32x4 acc[4][4] = {};
    for (int k0 = 0; k0 < 2048; k0 += 32) {
      const int cA0 = wid * 16, cA1 = (wid + 4) * 16;
      gl_lds16(&X[(size_t)(m0 + cA0 + sr) * 2048 + k0 + sc], &As[cA0 * 32]);
      gl_lds16(&X[(size_t)(m0 + cA1 + sr) * 2048 + k0 + sc], &As[cA1 * 32]);
      gl_lds16(&W[(size_t)(n0 + cA0 + sr) * 2048 + k0 + sc], &Bs[cA0 * 32]);
      gl_lds16(&W[(size_t)(n0 + cA1 + sr) * 2048 + k0 + sc], &Bs[cA1 * 32]);
      __syncthreads();
      bf16x8 af[4], bfr[4];
#pragma unroll
      for (int t = 0; t < 4; ++t) {
        af[t]  = *(const bf16x8*)&As[(wm * 64 + t * 16 + fr) * 32 + kg * 8];
        bfr[t] = *(const bf16x8*)&Bs[(wn * 64 + t * 16 + fr) * 32 + kg * 8];
      }
#pragma unroll
      for (int mt = 0; mt < 4; ++mt)
#pragma unroll
        for (int nt = 0; nt < 4; ++nt)
          acc[mt][nt] = __builtin_amdgcn_mfma_f32_16x16x32_bf16(af[mt], bfr[nt], acc[mt][nt], 0, 0, 0);
      __syncthreads();
    }
#pragma unroll
    for (int mt = 0; mt < 4; ++mt)
#pragma unroll
      for (int nt = 0; nt < 4; ++nt) {
        const int col = n0 + wn * 64 + nt * 16 + fr;
#pragma unroll
        for (int r = 0; r < 4; ++r) {
          const int row = m0 + wm * 64 + mt * 16 + kg * 4 + r;
          float v = acc[mt][nt][r];
          v = v / (1.f + __expf(-v));
          OUT[(size_t)row * 2048 + col] = v;
        }
      }
    return;
  }
  // --------------------------- scan (1 wave) --------------------------------
  if (threadIdx.x >= 64) return;
  const int bid = blockIdx.x;          // b*32 + h
  const int h = bid & 31, b = bid >> 5;
  const int lane = threadIdx.x;

  half2v aw[32];
  const float* Ar = Aw + (size_t)(h * 64 + lane) * 64;
#pragma unroll
  for (int j4 = 0; j4 < 16; ++j4) {
    float4 v = *(const float4*)&Ar[j4 * 4];
    aw[2 * j4]     = pkrtz(v.x, v.y);
    aw[2 * j4 + 1] = pkrtz(v.z, v.w);
  }

  const float* dBp = dB + (size_t)bid * L_SEQ * 64 + lane;
  unsigned short* stp = states + (size_t)bid * L_SEQ * 64 + lane;
  const float* dtp = dt + b * L_SEQ;

  float r0[4], r1[4];
#pragma unroll
  for (int u = 0; u < 4; ++u) r0[u] = dBp[(size_t)u * 64];
#pragma unroll
  for (int u = 0; u < 4; ++u) r1[u] = dBp[(size_t)(4 + u) * 64];
  float4 dtc = *(const float4*)&dtp[0];
  float4 dtn = *(const float4*)&dtp[4];

  float s = 0.f;
  for (int g = 0; g < L_SEQ / 4; ++g) {
    const int l0 = g * 4;
    const int lp = (l0 + 8 <= L_SEQ - 4) ? (l0 + 8) : (L_SEQ - 4);
    float rn[4];
#pragma unroll
    for (int u = 0; u < 4; ++u) rn[u] = dBp[(size_t)(lp + u) * 64];
    float4 dtn2 = *(const float4*)&dtp[lp];
    const float dtu[4] = { dtc.x, dtc.y, dtc.z, dtc.w };
#pragma unroll
    for (int u = 0; u < 4; ++u) {
      // pair dword: lanes 2p and 2p+1 both build (s[2p], s[2p+1])
      float sn = qperm<0xB1>(s);
      float lo = (lane & 1) ? sn : s;
      float hi = (lane & 1) ? s : sn;
      int dbits = __builtin_bit_cast(int, pkrtz(lo, hi));
      // wave-uniform broadcast: 32 readlanes -> SGPRs (no memory, no DS pipe)
      int wp[32];
#pragma unroll
      for (int p = 0; p < 32; ++p)
        wp[p] = __builtin_amdgcn_readlane(dbits, 2 * p);
      float a0 = 0.f, a1 = 0.f, a2 = 0.f, a3 = 0.f;
#pragma unroll
      for (int j = 0; j < 8; ++j) {
        a0 = __builtin_amdgcn_fdot2(__builtin_bit_cast(half2v, wp[j]),      aw[j],      a0, false);
        a1 = __builtin_amdgcn_fdot2(__builtin_bit_cast(half2v, wp[8 + j]),  aw[8 + j],  a1, false);
        a2 = __builtin_amdgcn_fdot2(__builtin_bit_cast(half2v, wp[16 + j]), aw[16 + j], a2, false);
        a3 = __builtin_amdgcn_fdot2(__builtin_bit_cast(half2v, wp[24 + j]), aw[24 + j], a3, false);
      }
      const float dot = (a0 + a1) + (a2 + a3);
      const float x = dot * dtu[u];
      const float e = __builtin_fmaf(x * x, 0.5f, 1.f + x);   // exp(x), |x| tiny
      s = e * s + r0[u];
      stp[(size_t)(l0 + u) * 64] = f2bf(s);
    }
#pragma unroll
    for (int u = 0; u < 4; ++u) { r0[u] = r1[u]; r1[u] = rn[u]; }
    dtc = dtn; dtn = dtn2;
  }
}

// ----- C projection + x*D + silu(gate) multiply; writes hs1 (b,l,hid) f32 -----
__global__ __launch_bounds__(256) void proj_k(const unsigned short* __restrict__ st,
                                              const unsigned short* __restrict__ cwb,
                                              const float* __restrict__ xin,
                                              const float* __restrict__ Dp,
                                              const float* __restrict__ gs,
                                              float* __restrict__ hs1) {
  const int l0 = blockIdx.x * 64, h = blockIdx.y, b = blockIdx.z;
  const int tid = threadIdx.x, lane = tid & 63, wid = tid >> 6;
  const int fr = lane & 15, kg = lane >> 4, wm = wid;
  f32x4 acc[4] = {};
#pragma unroll
  for (int ks = 0; ks < 2; ++ks) {
    bf16x8 a = *(const bf16x8*)&st[((size_t)(b * NH + h) * L_SEQ + l0 + wm * 16 + fr) * 64 + ks * 32 + kg * 8];
#pragma unroll
    for (int nt = 0; nt < 4; ++nt) {
      bf16x8 bq = *(const bf16x8*)&cwb[(size_t)(h * 64 + nt * 16 + fr) * 64 + ks * 32 + kg * 8];
      acc[nt] = __builtin_amdgcn_mfma_f32_16x16x32_bf16(a, bq, acc[nt], 0, 0, 0);
    }
  }
  const float Dh = Dp[h];
#pragma unroll
  for (int nt = 0; nt < 4; ++nt) {
    const int ccol = h * 64 + nt * 16 + fr;
#pragma unroll
    for (int r = 0; r < 4; ++r) {
      const int lg = l0 + wm * 16 + kg * 4 + r;
      const size_t idx = (size_t)(b * L_SEQ + lg) * HIDN + ccol;
      float v = acc[nt][r] + xin[idx] * Dh;
      hs1[idx] = v * gs[idx];
    }
  }
}

// --------------------- gated RMSNorm -> bf16 rows -----------------------------
__global__ __launch_bounds__(256) void norm_k(const float* __restrict__ hs1,
                                              const float* __restrict__ nw,
                                              unsigned short* __restrict__ out) {
  const int row = blockIdx.x;
  const float* p = hs1 + (size_t)row * HIDN;
  const int c0 = threadIdx.x * 8;
  float4 u0 = *(const float4*)&p[c0];
  float4 u1 = *(const float4*)&p[c0 + 4];
  float ss = u0.x * u0.x + u0.y * u0.y + u0.z * u0.z + u0.w * u0.w +
             u1.x * u1.x + u1.y * u1.y + u1.z * u1.z + u1.w * u1.w;
#pragma unroll
  for (int off = 32; off; off >>= 1) ss += __shfl_xor(ss, off);
  __shared__ float pr[4];
  if ((threadIdx.x & 63) == 0) pr[threadIdx.x >> 6] = ss;
  __syncthreads();
  float tot = pr[0] + pr[1] + pr[2] + pr[3];
  float rs = rsqrtf(tot * (1.f / HIDN) + 1e-6f);
  bf16x8 res;
  res[0] = (short)f2bf(nw[c0 + 0] * u0.x * rs);
  res[1] = (short)f2bf(nw[c0 + 1] * u0.y * rs);
  res[2] = (short)f2bf(nw[c0 + 2] * u0.z * rs);
  res[3] = (short)f2bf(nw[c0 + 3] * u0.w * rs);
  res[4] = (short)f2bf(nw[c0 + 4] * u1.x * rs);
  res[5] = (short)f2bf(nw[c0 + 5] * u1.y * rs);
  res[6] = (short)f2bf(nw[c0 + 6] * u1.z * rs);
  res[7] = (short)f2bf(nw[c0 + 7] * u1.w * rs);
  *(bf16x8*)&out[(size_t)row * HIDN + c0] = res;
}

extern "C" void kernel_launch(void* const* d_in, const int* in_sizes, int n_in,
                              void* d_out, int out_size, void* d_ws, size_t ws_size,
                              hipStream_t stream) {
  const float* x  = (const float*)d_in[0];
  const float* dt = (const float*)d_in[1];
  const float* gw = (const float*)d_in[2];
  const float* Aw = (const float*)d_in[3];
  const float* cw = (const float*)d_in[4];
  const float* cb = (const float*)d_in[5];
  const float* Cw = (const float*)d_in[6];
  const float* Dp = (const float*)d_in[7];
  const float* nw = (const float*)d_in[8];
  const float* ow = (const float*)d_in[9];
  float* out = (float*)d_out;

  // workspace layout (bytes). states overlays hsb (states' last reader proj_k
  // completes before norm_k writes hsb); hs1 overlays dBf (free after scan).
  char* w = (char*)d_ws;
  unsigned short* xb   = (unsigned short*)(w);                // 32MB
  unsigned short* gwb  = (unsigned short*)(w + 33554432);     // 8MB
  unsigned short* owb  = (unsigned short*)(w + 41943040);     // 8MB
  unsigned short* wret = (unsigned short*)(w + 50331648);     // 1MB
  unsigned short* cwb  = (unsigned short*)(w + 51380224);     // 256KB
  float*          dBf  = (float*)(w + 52428800);              // 64MB
  float*          hs1  = dBf;                                 // overlay (after scan)
  unsigned short* hsb  = (unsigned short*)(w + 119537664);    // 32MB
  unsigned short* stb  = hsb;                                 // overlay (before norm)
  if (ws_size < 153092096) return;

  cvt_bf16_k<<<2048, 256, 0, stream>>>(x, xb, 16777216 / 4);
  cvt_bf16_k<<<1024, 256, 0, stream>>>(gw, gwb, 4194304 / 4);
  cvt_bf16_k<<<1024, 256, 0, stream>>>(ow, owb, 4194304 / 4);
  cvt_bf16_k<<<128, 256, 0, stream>>>(Cw, cwb, 131072 / 4);
  wret_k<<<2048, 256, 0, stream>>>(cw, wret);

  conv_k<<<dim3(32, 32, 4), 256, 0, stream>>>(xb, wret, cb, dt, dBf);
  // scan (blocks 0..127) || gate GEMM + silu (blocks 128..1151)
  scan_gemm_k<<<1152, 256, 0, stream>>>(dBf, Aw, dt, stb, xb, gwb, out);
  proj_k<<<dim3(32, 32, 4), 256, 0, stream>>>(stb, cwb, x, Dp, out, hs1);
  norm_k<<<8192, 256, 0, stream>>>(hs1, nw, hsb);
  gemm_xwt_k<0><<<dim3(64, 16), 256, 0, stream>>>(hsb, owb, out, 8192, 2048, 2048);
}